// Round 1
// baseline (54.525 us; speedup 1.0000x reference)
//
#include <hip/hip_runtime.h>

// WiSARD inference: B=4096 samples, ENTRY=1024 bits, TUPLE=16, CLASSES=10,
// NEURONS=64, ADDR_SPACE=2^16.
// out[b][c] = sum_n ram[c][n][addr(b,c,n)],
// addr(b,c,n) = sum_t samples[b][tm[c][n*16+t]] << (15-t)

#define BATCH      4096
#define ENTRY      1024
#define TUPLE      16
#define CLASSES    10
#define NEURONS    64

// ---------------- Kernel 1: bit-pack samples ----------------
// One wave per sample. 16 ballot iterations of 64 bits each -> 1024 bits.
// packed64[s*16 + t] bit L = samples[s][t*64 + L] & 1
__global__ __launch_bounds__(256) void pack_kernel(
    const int* __restrict__ samples,
    unsigned long long* __restrict__ packed64)
{
    const int gtid = blockIdx.x * 256 + threadIdx.x;
    const int wave = gtid >> 6;       // sample index, 0..4095
    const int lane = gtid & 63;
    const int* sp = samples + (size_t)wave * ENTRY;
#pragma unroll
    for (int t = 0; t < 16; ++t) {
        int v = sp[t * 64 + lane];
        unsigned long long m = __ballot(v & 1);
        if (lane == 0) packed64[wave * 16 + t] = m;
    }
}

// ---------------- Kernel 2: classify ----------------
// One wave per (sample, class). lane = neuron.
// Block = 256 threads = 4 waves = 4 samples of one class.
// grid = CLASSES * (BATCH/4) = 10240 blocks.
__global__ __launch_bounds__(256) void wisard_kernel(
    const int* __restrict__ tm,          // [CLASSES][ENTRY]
    const float* __restrict__ ram,       // [CLASSES][NEURONS][65536]
    const unsigned* __restrict__ packed, // [BATCH][32]
    float* __restrict__ out)             // [BATCH][CLASSES]
{
    const int tid  = threadIdx.x;
    const int lane = tid & 63;           // neuron index
    const int wid  = tid >> 6;           // wave-in-block 0..3
    const int bid  = blockIdx.x;
    const int c    = bid >> 10;                    // class (1024 blocks/class)
    const int s    = ((bid & 1023) << 2) | wid;    // sample

    // 16 tuple indices for this (class, neuron): lane-contiguous 64B loads.
    const int4* tmp4 = reinterpret_cast<const int4*>(tm + c * ENTRY + lane * TUPLE);
    const int4 t0 = tmp4[0];
    const int4 t1 = tmp4[1];
    const int4 t2 = tmp4[2];
    const int4 t3 = tmp4[3];

    // Each lane holds one packed word of this wave's sample (words 0..31,
    // duplicated across the two half-waves). Arbitrary words via shfl.
    const unsigned myword = packed[s * 32 + (lane & 31)];

    unsigned addr = 0;
#define WSTEP(E)                                                 \
    {                                                            \
        const int  w_   = (E) >> 5;                              \
        const int  b_   = (E) & 31;                              \
        const unsigned word_ = (unsigned)__shfl((int)myword, w_);\
        addr = (addr << 1) | ((word_ >> b_) & 1u);               \
    }
    WSTEP(t0.x) WSTEP(t0.y) WSTEP(t0.z) WSTEP(t0.w)
    WSTEP(t1.x) WSTEP(t1.y) WSTEP(t1.z) WSTEP(t1.w)
    WSTEP(t2.x) WSTEP(t2.y) WSTEP(t2.z) WSTEP(t2.w)
    WSTEP(t3.x) WSTEP(t3.y) WSTEP(t3.z) WSTEP(t3.w)
#undef WSTEP

    // Gather: one float per lane.
    const unsigned ridx = (((unsigned)(c * NEURONS + lane)) << 16) | addr;
    float v = ram[ridx];

    // Sum over the 64 neurons (full-wave butterfly reduction).
#pragma unroll
    for (int off = 32; off > 0; off >>= 1)
        v += __shfl_xor(v, off);

    if (lane == 0) out[s * CLASSES + c] = v;
}

extern "C" void kernel_launch(void* const* d_in, const int* in_sizes, int n_in,
                              void* d_out, int out_size, void* d_ws, size_t ws_size,
                              hipStream_t stream)
{
    const int*   samples = (const int*)d_in[0];
    const int*   tm      = (const int*)d_in[1];
    const float* ram     = (const float*)d_in[2];
    float*       out     = (float*)d_out;

    unsigned long long* packed64 = (unsigned long long*)d_ws; // 4096*16*8 = 512 KB

    // Pack: 4096 waves, 4 waves/block -> 1024 blocks.
    pack_kernel<<<BATCH / 4, 256, 0, stream>>>(samples, packed64);

    // Classify: 40960 waves, 4 waves/block -> 10240 blocks.
    wisard_kernel<<<CLASSES * (BATCH / 4), 256, 0, stream>>>(
        tm, ram, (const unsigned*)packed64, out);
}